// Round 5
// baseline (119.113 us; speedup 1.0000x reference)
//
#include <hip/hip_runtime.h>

// Node2VecSkipGram loss on MI355X — round 5.
// Change vs round 4: 8-lanes-per-row layout. Each 8-lane group owns one batch
// element; lane gl loads float4 at float4-index (gl + q*8), q=0..3 — each
// instruction reads 128B contiguous per group (same cache lines, same VMEM
// instruction count), but the butterfly is 3 steps and one shuffle instruction
// reduces 8 elements at once: 52.5 -> 7.9 shuffles/element.
// Loss stays in round-4 product form (verified):
//   loss = log( (1+e^{-s_pos}) * prod_k (1+e^{s_k}) )

constexpr int NNEG = 20;
constexpr int D = 128;        // 32 float4 per row
constexpr int NBLOCKS = 2048; // 8192 waves * 8 elem/wave = 65536 = exactly one pass

__global__ __launch_bounds__(256) void n2v_loss_kernel(
    const int* __restrict__ center_nodes,
    const int* __restrict__ context_nodes,
    const int* __restrict__ negative_nodes,
    const float* __restrict__ center_w,
    const float* __restrict__ context_w,
    float* __restrict__ block_partials,
    int batch)
{
    const int lane  = threadIdx.x & 63;
    const int grp   = lane >> 3;      // 0..7: which element slot this group owns
    const int gl    = lane & 7;       // lane within group: float4 index gl + q*8
    const int wave  = threadIdx.x >> 6;
    const int wpb   = blockDim.x >> 6;
    const int gwave = blockIdx.x * wpb + wave;
    const int nwav  = gridDim.x * wpb;

    float acc = 0.0f;

    for (int b0 = gwave * 8; b0 < batch; b0 += nwav * 8) {
        const int b = b0 + grp;
        float loss = 0.0f;

        if (b < batch) {
            const int ci = center_nodes[b];   // broadcast within group
            const int xi = context_nodes[b];

            const float4* crow = reinterpret_cast<const float4*>(center_w  + (size_t)ci * D);
            const float4* xrow = reinterpret_cast<const float4*>(context_w + (size_t)xi * D);

            float4 ce[4];
#pragma unroll
            for (int q = 0; q < 4; ++q) ce[q] = crow[gl + q * 8];

            // negative indices: 20 ints = 5x int4, broadcast within group
            int nb[NNEG];
            {
                const int4* np4 = reinterpret_cast<const int4*>(negative_nodes + (size_t)b * NNEG);
#pragma unroll
                for (int q = 0; q < 5; ++q) {
                    const int4 v = np4[q];
                    nb[q * 4 + 0] = v.x; nb[q * 4 + 1] = v.y;
                    nb[q * 4 + 2] = v.z; nb[q * 4 + 3] = v.w;
                }
            }

            float sc[NNEG + 1];
            {
                float d0 = 0.0f, d1 = 0.0f, d2 = 0.0f, d3 = 0.0f;
#pragma unroll
                for (int q = 0; q < 4; ++q) {
                    const float4 xe = xrow[gl + q * 8];
                    d0 = fmaf(ce[q].x, xe.x, d0);
                    d1 = fmaf(ce[q].y, xe.y, d1);
                    d2 = fmaf(ce[q].z, xe.z, d2);
                    d3 = fmaf(ce[q].w, xe.w, d3);
                }
                sc[0] = (d0 + d1) + (d2 + d3);
            }

#pragma unroll
            for (int k = 0; k < NNEG; ++k) {
                const float4* nrow =
                    reinterpret_cast<const float4*>(context_w + (size_t)nb[k] * D);
                float d0 = 0.0f, d1 = 0.0f, d2 = 0.0f, d3 = 0.0f;
#pragma unroll
                for (int q = 0; q < 4; ++q) {
                    const float4 ne = nrow[gl + q * 8];
                    d0 = fmaf(ce[q].x, ne.x, d0);
                    d1 = fmaf(ce[q].y, ne.y, d1);
                    d2 = fmaf(ce[q].z, ne.z, d2);
                    d3 = fmaf(ce[q].w, ne.w, d3);
                }
                sc[k + 1] = (d0 + d1) + (d2 + d3);
            }

            // 21 intra-group (8-lane) butterflies: one instruction reduces all
            // 8 elements of the wave at once
#pragma unroll
            for (int k = 0; k <= NNEG; ++k) {
                float v = sc[k];
#pragma unroll
                for (int off = 4; off > 0; off >>= 1)
                    v += __shfl_xor(v, off, 64);
                sc[k] = v;
            }

            // product-form loss: 21 factors, two independent accumulators
            float p0 = 1.0f + __expf(-sc[0]);
            float p1 = 1.0f;
#pragma unroll
            for (int k = 1; k <= NNEG - 1; k += 2)   // 1,3,...,19
                p0 *= (1.0f + __expf(sc[k]));
#pragma unroll
            for (int k = 2; k <= NNEG; k += 2)       // 2,4,...,20
                p1 *= (1.0f + __expf(sc[k]));
            loss = __logf(p0 * p1);
        }

        acc += loss;   // uniform within each 8-lane group
    }

    // cross-group combine: after these, every lane holds the wave total
    acc += __shfl_xor(acc, 8, 64);
    acc += __shfl_xor(acc, 16, 64);
    acc += __shfl_xor(acc, 32, 64);

    __shared__ float wsum[8];
    if (lane == 0) wsum[wave] = acc;
    __syncthreads();
    if (threadIdx.x == 0) {
        float s = 0.0f;
        for (int w = 0; w < wpb; ++w) s += wsum[w];
        block_partials[blockIdx.x] = s;
    }
}

__global__ __launch_bounds__(256) void n2v_reduce_kernel(
    const float* __restrict__ partials, int n, float inv_batch,
    float* __restrict__ out)
{
    __shared__ float sm[256];
    float v = 0.0f;
    for (int i = threadIdx.x; i < n; i += 256) v += partials[i];
    sm[threadIdx.x] = v;
    __syncthreads();
    for (int s = 128; s > 0; s >>= 1) {
        if (threadIdx.x < s) sm[threadIdx.x] += sm[threadIdx.x + s];
        __syncthreads();
    }
    if (threadIdx.x == 0) out[0] = sm[0] * inv_batch;
}

extern "C" void kernel_launch(void* const* d_in, const int* in_sizes, int n_in,
                              void* d_out, int out_size, void* d_ws, size_t ws_size,
                              hipStream_t stream) {
    const int*   center_nodes   = (const int*)d_in[0];
    const int*   context_nodes  = (const int*)d_in[1];
    const int*   negative_nodes = (const int*)d_in[2];
    const float* center_w       = (const float*)d_in[3];
    const float* context_w      = (const float*)d_in[4];
    float*       out            = (float*)d_out;
    const int    batch          = in_sizes[0];

    float* partials = (float*)d_ws;

    n2v_loss_kernel<<<NBLOCKS, 256, 0, stream>>>(
        center_nodes, context_nodes, negative_nodes,
        center_w, context_w, partials, batch);

    n2v_reduce_kernel<<<1, 256, 0, stream>>>(
        partials, NBLOCKS, 1.0f / (float)batch, out);
}